// Round 1
// baseline (476.582 us; speedup 1.0000x reference)
//
#include <hip/hip_runtime.h>

#define N_NODES   50000
#define N_EDGES   800000
#define IN_DIM    89
#define HID       128
#define N_CLASSES 64
#define N_GRAPHS  64

// ---------------------------------------------------------------------------
// row_ptr via binary search: dst is sorted, graph_id is sorted.
// node_ptr[v] = lower_bound(dst, v), v in [0, N_NODES]
// graph_ptr[g] = lower_bound(graph_id, g), g in [0, N_GRAPHS]
// ---------------------------------------------------------------------------
__global__ void rowptr_kernel(const int* __restrict__ dst,
                              const int* __restrict__ gid,
                              int* __restrict__ node_ptr,
                              int* __restrict__ graph_ptr) {
    int i = blockIdx.x * blockDim.x + threadIdx.x;
    if (i <= N_NODES) {
        int lo = 0, hi = N_EDGES;
        while (lo < hi) { int mid = (lo + hi) >> 1; if (dst[mid] < i) lo = mid + 1; else hi = mid; }
        node_ptr[i] = lo;
    }
    if (i <= N_GRAPHS) {
        int lo = 0, hi = N_NODES;
        while (lo < hi) { int mid = (lo + hi) >> 1; if (gid[mid] < i) lo = mid + 1; else hi = mid; }
        graph_ptr[i] = lo;
    }
}

// ---------------------------------------------------------------------------
// Mean aggregation over incoming edges (dst-sorted CSR, no atomics).
// One block (128 threads) per node; each edge is one coalesced row read.
// ---------------------------------------------------------------------------
template <int DIM>
__global__ void agg_kernel(const float* __restrict__ h,
                           const int* __restrict__ src,
                           const int* __restrict__ node_ptr,
                           float* __restrict__ out) {
    const int v   = blockIdx.x;
    const int tid = threadIdx.x;           // blockDim = 128
    const int lo  = node_ptr[v];
    const int hi  = node_ptr[v + 1];
    const float inv = 1.0f / (float)max(hi - lo, 1);

    __shared__ int s_src[128];
    float acc = 0.0f;
    for (int base = lo; base < hi; base += 128) {
        const int n = min(128, hi - base);
        if (tid < n) s_src[tid] = src[base + tid];
        __syncthreads();
        for (int e = 0; e < n; ++e) {
            const int u = s_src[e];
            if (tid < DIM) acc += h[(long)u * DIM + tid];
        }
        __syncthreads();
    }
    if (tid < DIM) out[(long)v * DIM + tid] = acc * inv;
}

// ---------------------------------------------------------------------------
// Y[M x N] = act(X[M x K] @ W[K x N] + b), N == blockDim.x (128).
// 16 rows per block; X tile staged in LDS; W reads coalesced, reused 16x.
// ---------------------------------------------------------------------------
template <int K, int N, bool RELU>
__global__ void linear_kernel(const float* __restrict__ X,
                              const float* __restrict__ W,
                              const float* __restrict__ b,
                              float* __restrict__ Y, int M) {
    constexpr int R = 16;
    __shared__ float xs[R][K + 1];
    const int row0 = blockIdx.x * R;
    const int j    = threadIdx.x;

    for (int idx = threadIdx.x; idx < R * K; idx += N) {
        const int r = idx / K, k = idx - r * K;
        const int row = row0 + r;
        xs[r][k] = (row < M) ? X[(long)row * K + k] : 0.0f;
    }
    __syncthreads();

    float acc[R];
    const float bj = b[j];
#pragma unroll
    for (int r = 0; r < R; ++r) acc[r] = bj;

    for (int k = 0; k < K; ++k) {
        const float wv = W[k * N + j];
#pragma unroll
        for (int r = 0; r < R; ++r) acc[r] += xs[r][k] * wv;
    }

#pragma unroll
    for (int r = 0; r < R; ++r) {
        const int row = row0 + r;
        if (row < M) {
            float v = acc[r];
            if (RELU) v = fmaxf(v, 0.0f);
            Y[(long)row * N + j] = v;
        }
    }
}

// ---------------------------------------------------------------------------
// Per-graph mean pooling (graph_id sorted). 8 partial blocks per graph,
// partial sums joined with atomicAdd (hg pre-zeroed).
// ---------------------------------------------------------------------------
__global__ void pool_kernel(const float* __restrict__ h,
                            const int* __restrict__ graph_ptr,
                            float* __restrict__ hg) {
    constexpr int SPLIT = 8;
    const int g   = blockIdx.x / SPLIT;
    const int s   = blockIdx.x % SPLIT;
    const int tid = threadIdx.x;            // 128
    const int lo  = graph_ptr[g];
    const int hi  = graph_ptr[g + 1];
    const float inv = 1.0f / (float)max(hi - lo, 1);

    float acc = 0.0f;
    for (int r = lo + s; r < hi; r += SPLIT)
        acc += h[(long)r * HID + tid];
    if (acc != 0.0f || s == 0)
        atomicAdd(&hg[g * HID + tid], acc * inv);
}

// ---------------------------------------------------------------------------
// Classifier head.
// ---------------------------------------------------------------------------
__global__ void cls1_kernel(const float* __restrict__ hg,
                            const float* __restrict__ Wc1,
                            const float* __restrict__ bc1,
                            float* __restrict__ t) {
    const int g = blockIdx.x;               // 64
    const int j = threadIdx.x;              // 128
    __shared__ float row[HID];
    row[j] = hg[g * HID + j];
    __syncthreads();
    float acc = bc1[j];
    for (int k = 0; k < HID; ++k) acc += row[k] * Wc1[k * HID + j];
    t[g * HID + j] = fmaxf(acc, 0.0f);
}

__global__ void cls2_kernel(const float* __restrict__ t,
                            const float* __restrict__ Wc2,
                            const float* __restrict__ bc2,
                            float* __restrict__ out) {
    const int g = blockIdx.x;               // 64
    const int j = threadIdx.x;              // 64
    __shared__ float row[HID];
    row[j]      = t[g * HID + j];
    row[j + 64] = t[g * HID + j + 64];
    __syncthreads();
    float acc = bc2[j];
    for (int k = 0; k < HID; ++k) acc += row[k] * Wc2[k * N_CLASSES + j];
    out[g * N_CLASSES + j] = acc;
}

// ---------------------------------------------------------------------------
extern "C" void kernel_launch(void* const* d_in, const int* in_sizes, int n_in,
                              void* d_out, int out_size, void* d_ws, size_t ws_size,
                              hipStream_t stream) {
    const float* nf   = (const float*)d_in[0];
    const int*   src  = (const int*)  d_in[1];
    const int*   dst  = (const int*)  d_in[2];
    const int*   gid  = (const int*)  d_in[3];
    // d_in[4] = n_graphs scalar (compile-time constant here)
    const float* W1  = (const float*)d_in[5];
    const float* b1  = (const float*)d_in[6];
    const float* W2  = (const float*)d_in[7];
    const float* b2  = (const float*)d_in[8];
    const float* W3  = (const float*)d_in[9];
    const float* b3  = (const float*)d_in[10];
    const float* Wc1 = (const float*)d_in[11];
    const float* bc1 = (const float*)d_in[12];
    const float* Wc2 = (const float*)d_in[13];
    const float* bc2 = (const float*)d_in[14];
    float* out = (float*)d_out;

    // Workspace layout (256 B aligned)
    char* ws = (char*)d_ws;
    size_t off = 0;
    auto alloc = [&](size_t bytes) { void* p = ws + off; off = (off + bytes + 255) & ~(size_t)255; return p; };
    int*   node_ptr  = (int*)  alloc((N_NODES + 1) * sizeof(int));
    int*   graph_ptr = (int*)  alloc((N_GRAPHS + 1) * sizeof(int));
    float* aggbuf    = (float*)alloc((size_t)N_NODES * HID * sizeof(float)); // also holds 89-dim agg
    float* hA        = (float*)alloc((size_t)N_NODES * HID * sizeof(float));
    float* hB        = (float*)alloc((size_t)N_NODES * HID * sizeof(float));
    float* hg        = (float*)alloc(N_GRAPHS * HID * sizeof(float));
    float* tbuf      = (float*)alloc(N_GRAPHS * HID * sizeof(float));
    (void)ws_size;

    // 1. CSR pointers
    rowptr_kernel<<<(N_NODES + 256) / 256, 256, 0, stream>>>(dst, gid, node_ptr, graph_ptr);

    // 2. Layer 1: agg(nf) [89] -> linear 89->128 + relu
    agg_kernel<IN_DIM><<<N_NODES, 128, 0, stream>>>(nf, src, node_ptr, aggbuf);
    linear_kernel<IN_DIM, HID, true><<<(N_NODES + 15) / 16, HID, 0, stream>>>(aggbuf, W1, b1, hA, N_NODES);

    // 3. Layer 2
    agg_kernel<HID><<<N_NODES, 128, 0, stream>>>(hA, src, node_ptr, aggbuf);
    linear_kernel<HID, HID, true><<<(N_NODES + 15) / 16, HID, 0, stream>>>(aggbuf, W2, b2, hB, N_NODES);

    // 4. Layer 3
    agg_kernel<HID><<<N_NODES, 128, 0, stream>>>(hB, src, node_ptr, aggbuf);
    linear_kernel<HID, HID, true><<<(N_NODES + 15) / 16, HID, 0, stream>>>(aggbuf, W3, b3, hA, N_NODES);

    // 5. Graph mean pool
    hipMemsetAsync(hg, 0, N_GRAPHS * HID * sizeof(float), stream);
    pool_kernel<<<N_GRAPHS * 8, HID, 0, stream>>>(hA, graph_ptr, hg);

    // 6. Classifier head
    cls1_kernel<<<N_GRAPHS, HID, 0, stream>>>(hg, Wc1, bc1, tbuf);
    cls2_kernel<<<N_GRAPHS, N_CLASSES, 0, stream>>>(tbuf, Wc2, bc2, out);
}